// Round 6
// baseline (641.465 us; speedup 1.0000x reference)
//
#include <hip/hip_runtime.h>
#include <hip/hip_fp16.h>

#define N_NODES 50000
#define N_EDGES 500000
#define DIM 64
#define KDIM 4
#define HID 64
#define NCLS 40
#define NBLK ((N_NODES + 255) / 256)   // 196
#define EBLK ((N_EDGES + 255) / 256)   // 1954

typedef unsigned uv4 __attribute__((ext_vector_type(4)));

__device__ inline unsigned pack2(float a, float b) {
    __half2 h = __floats2half2_rn(a, b);
    return *(unsigned*)&h;
}
__device__ inline float2 unpack2(unsigned u) {
    __half2 h = *(__half2*)&u;
    return __half22float2(h);
}
__device__ inline uint4 ldnt4(const uint4* p) {
    uv4 v = __builtin_nontemporal_load((const uv4*)p);
    return make_uint4(v.x, v.y, v.z, v.w);
}
__device__ inline void stnt4(uint4* p, uint4 v) {
    uv4 w = {v.x, v.y, v.z, v.w};
    __builtin_nontemporal_store(w, (uv4*)p);
}

// ---- histogram of dst (in-degree) ----
__global__ void hist_k(const int* __restrict__ dst, int* __restrict__ cnt) {
    int e = blockIdx.x * 256 + threadIdx.x;
    if (e < N_EDGES) atomicAdd(&cnt[dst[e]], 1);
}

// ---- single-kernel scan: per-block scan + publish + parallel lookback ----
__global__ __launch_bounds__(256) void scan_k(const int* __restrict__ cnt,
                                              int* __restrict__ start,
                                              int* __restrict__ cursor,
                                              volatile int* __restrict__ bflag,
                                              volatile int* __restrict__ bval) {
    __shared__ int ls[256];
    __shared__ int sbase;
    __shared__ int ok_all;
    int b = blockIdx.x, t = threadIdx.x;
    int n = b * 256 + t;
    int v = (n < N_NODES) ? cnt[n] : 0;
    ls[t] = v;
    __syncthreads();
#pragma unroll
    for (int off = 1; off < 256; off <<= 1) {
        int u = (t >= off) ? ls[t - off] : 0;
        __syncthreads();
        ls[t] += u;
        __syncthreads();
    }
    int incl = ls[t];
    int total = ls[255];
    __syncthreads();

    if (t == 0) {
        bval[b] = total;
        __threadfence();
        bflag[b] = 1;
    }

    if (b > 0) {
        for (;;) {
            int f = (t < b) ? bflag[t] : 1;
            if (t == 0) ok_all = 1;
            __syncthreads();
            if (!f) ok_all = 0;
            __syncthreads();
            if (ok_all) break;
        }
        __threadfence();
        int pv = (t < b) ? bval[t] : 0;
        ls[t] = pv;
        __syncthreads();
#pragma unroll
        for (int off = 128; off > 0; off >>= 1) {
            if (t < off) ls[t] += ls[t + off];
            __syncthreads();
        }
        if (t == 0) sbase = ls[0];
        __syncthreads();
    } else {
        if (t == 0) sbase = 0;
        __syncthreads();
    }

    int excl = sbase + incl - v;
    if (n < N_NODES) { start[n] = excl; cursor[n] = excl; }
    if (n == 0) start[N_NODES] = N_EDGES;
}

// ---- degree-sort: 256-bin histogram (key = 255 - clamped degree, LPT order) ----
__global__ void dhist_k(const int* __restrict__ cnt, int* __restrict__ dbin) {
    int n = blockIdx.x * 256 + threadIdx.x;
    if (n < N_NODES) {
        int d = cnt[n]; if (d > 255) d = 255;
        atomicAdd(&dbin[255 - d], 1);
    }
}

// single block exclusive scan of 256 bins -> dcursor
__global__ __launch_bounds__(256) void dscan_k(const int* __restrict__ dbin,
                                               int* __restrict__ dcursor) {
    __shared__ int ls[256];
    int t = threadIdx.x;
    int v = dbin[t];
    ls[t] = v;
    __syncthreads();
#pragma unroll
    for (int off = 1; off < 256; off <<= 1) {
        int u = (t >= off) ? ls[t - off] : 0;
        __syncthreads();
        ls[t] += u;
        __syncthreads();
    }
    dcursor[t] = ls[t] - v;   // exclusive
}

__global__ void dscatter_k(const int* __restrict__ cnt, int* __restrict__ dcursor,
                           int* __restrict__ perm) {
    int n = blockIdx.x * 256 + threadIdx.x;
    if (n < N_NODES) {
        int d = cnt[n]; if (d > 255) d = 255;
        int pos = atomicAdd(&dcursor[255 - d], 1);
        perm[pos] = n;
    }
}

// ---- counting-sort scatter: write ONLY recA (16B random store/edge),
//      keep edge index in .w so recB can be built by a streaming repack ----
__global__ void scatter_k(const int* __restrict__ src, const int* __restrict__ dst,
                          const float* __restrict__ ef, int* __restrict__ cursor,
                          uint4* __restrict__ recA) {
    int e = blockIdx.x * 256 + threadIdx.x;
    if (e < N_EDGES) {
        int d = dst[e];
        int pos = atomicAdd(&cursor[d], 1);
        int sn = src[e];
        float4 f0 = ((const float4*)ef)[e];
        stnt4(&recA[pos], make_uint4((unsigned)sn, pack2(f0.x, f0.y), pack2(f0.z, f0.w), (unsigned)e));
    }
}

// ---- streaming repack: build layer-1 records from recA order ----
__global__ void repack_k(const uint4* __restrict__ recA, const float* __restrict__ ef1,
                         uint4* __restrict__ recB) {
    int i = blockIdx.x * 256 + threadIdx.x;
    if (i < N_EDGES) {
        uint4 r = ldnt4(&recA[i]);
        int e = (int)r.w;
        float4 f1 = ((const float4*)ef1)[e];
        stnt4(&recB[i], make_uint4(r.x, pack2(f1.x, f1.y), pack2(f1.z, f1.w), 0u));
    }
}

// ---- node transform, split-k: blockIdx.y = kpair (k in {2*kpair, 2*kpair+1}) ----
__global__ __launch_bounds__(256) void transform_k(const float* __restrict__ hin,
                                                   const float* __restrict__ W,
                                                   unsigned* __restrict__ y) {
    __shared__ float sW[2 * 64 * 64];      // 32 KB: two k-slices
    __shared__ float sh[64 * 65];          // 16.6 KB
    int t = threadIdx.x;
    int kpair = blockIdx.y;

    const float4* W4 = (const float4*)(W + (size_t)kpair * 2 * 4096);
    float4* sW4 = (float4*)sW;
#pragma unroll
    for (int i = 0; i < 8; ++i) sW4[t + 256 * i] = W4[t + 256 * i];

    int n0 = blockIdx.x * 64;
#pragma unroll
    for (int i = 0; i < 4; ++i) {
        int idx = t + 256 * i;        // 0..1023
        int nl = idx >> 4;            // 0..63
        int dg = idx & 15;
        int n = n0 + nl;
        float4 v = make_float4(0.f, 0.f, 0.f, 0.f);
        if (n < N_NODES) v = ((const float4*)hin)[(size_t)n * 16 + dg];
        sh[nl * 65 + dg * 4 + 0] = v.x;
        sh[nl * 65 + dg * 4 + 1] = v.y;
        sh[nl * 65 + dg * 4 + 2] = v.z;
        sh[nl * 65 + dg * 4 + 3] = v.w;
    }
    __syncthreads();

    int nl = t & 31;
    int cg = t >> 5;                  // 0..7
    int k_local = cg >> 2;            // 0..1
    int hc0 = (cg & 3) * 16;

    float acc0[16], acc1[16];
#pragma unroll
    for (int j = 0; j < 16; ++j) { acc0[j] = 0.f; acc1[j] = 0.f; }

    for (int d = 0; d < 64; ++d) {
        float a0 = sh[nl * 65 + d];
        float a1 = sh[(nl + 32) * 65 + d];
        const float* wr = &sW[k_local * 4096 + d * 64 + hc0];
#pragma unroll
        for (int j = 0; j < 16; ++j) {
            float w = wr[j];
            acc0[j] = fmaf(a0, w, acc0[j]);
            acc1[j] = fmaf(a1, w, acc1[j]);
        }
    }

    int n_a = n0 + nl, n_b = n0 + nl + 32;
    int cbase = (kpair * 2 + k_local) * 64 + hc0;
    if (n_a < N_NODES) {
        uint4* o = (uint4*)(y + ((size_t)n_a * 256 + cbase) / 2);
        o[0] = make_uint4(pack2(acc0[0], acc0[1]), pack2(acc0[2], acc0[3]),
                          pack2(acc0[4], acc0[5]), pack2(acc0[6], acc0[7]));
        o[1] = make_uint4(pack2(acc0[8], acc0[9]), pack2(acc0[10], acc0[11]),
                          pack2(acc0[12], acc0[13]), pack2(acc0[14], acc0[15]));
    }
    if (n_b < N_NODES) {
        uint4* o = (uint4*)(y + ((size_t)n_b * 256 + cbase) / 2);
        o[0] = make_uint4(pack2(acc1[0], acc1[1]), pack2(acc1[2], acc1[3]),
                          pack2(acc1[4], acc1[5]), pack2(acc1[6], acc1[7]));
        o[1] = make_uint4(pack2(acc1[8], acc1[9]), pack2(acc1[10], acc1[11]),
                          pack2(acc1[12], acc1[13]), pack2(acc1[14], acc1[15]));
    }
}

// ---- edge load/compute split for MLP ----
__device__ inline void load_edge(const uint4 r, const unsigned* __restrict__ y,
                                 int lane, uint2& q0, uint2& q1, uint2& q2, uint2& q3) {
    int sn = (int)r.x;
    const uint2* yb = (const uint2*)(y + (size_t)sn * 128);
    q0 = yb[lane];
    q1 = yb[16 + lane];
    q2 = yb[32 + lane];
    q3 = yb[48 + lane];
}

__device__ inline void compute_edge(const uint4 r, uint2 q0, uint2 q1, uint2 q2, uint2 q3,
                                    const float4 bias, float4& acc) {
    float2 e01 = unpack2(r.y);
    float2 e23 = unpack2(r.z);
    float2 a0 = unpack2(q0.x), a1 = unpack2(q0.y);
    float2 b0 = unpack2(q1.x), b1 = unpack2(q1.y);
    float2 c0 = unpack2(q2.x), c1 = unpack2(q2.y);
    float2 d0 = unpack2(q3.x), d1 = unpack2(q3.y);

    float4 z = bias;
    z.x = fmaf(e01.x, a0.x, z.x); z.y = fmaf(e01.x, a0.y, z.y);
    z.z = fmaf(e01.x, a1.x, z.z); z.w = fmaf(e01.x, a1.y, z.w);
    z.x = fmaf(e01.y, b0.x, z.x); z.y = fmaf(e01.y, b0.y, z.y);
    z.z = fmaf(e01.y, b1.x, z.z); z.w = fmaf(e01.y, b1.y, z.w);
    z.x = fmaf(e23.x, c0.x, z.x); z.y = fmaf(e23.x, c0.y, z.y);
    z.z = fmaf(e23.x, c1.x, z.z); z.w = fmaf(e23.x, c1.y, z.w);
    z.x = fmaf(e23.y, d0.x, z.x); z.y = fmaf(e23.y, d0.y, z.y);
    z.z = fmaf(e23.y, d1.x, z.z); z.w = fmaf(e23.y, d1.y, z.w);

    acc.x += fmaxf(z.x, 0.f);
    acc.y += fmaxf(z.y, 0.f);
    acc.z += fmaxf(z.z, 0.f);
    acc.w += fmaxf(z.w, 0.f);
}

// ---- aggregate core: unroll-4, batched loads; rec loads nontemporal ----
__device__ inline float4 agg_core(const uint4* __restrict__ rec,
                                  const int* __restrict__ start,
                                  const int* __restrict__ cnt,
                                  const unsigned* __restrict__ y,
                                  const float* __restrict__ b,
                                  int g, int lane) {
    int s0 = start[g];
    int deg = cnt[g];
    int s1 = s0 + deg;

    float4 bias = ((const float4*)b)[lane];
    float4 acc = make_float4(0.f, 0.f, 0.f, 0.f);

    int i = s0;
    for (; i + 4 <= s1; i += 4) {
        uint4 r0 = ldnt4(&rec[i + 0]);
        uint4 r1 = ldnt4(&rec[i + 1]);
        uint4 r2 = ldnt4(&rec[i + 2]);
        uint4 r3 = ldnt4(&rec[i + 3]);
        uint2 a0, a1, a2, a3, b0, b1, b2, b3, c0, c1, c2, c3, d0, d1, d2, d3;
        load_edge(r0, y, lane, a0, a1, a2, a3);
        load_edge(r1, y, lane, b0, b1, b2, b3);
        load_edge(r2, y, lane, c0, c1, c2, c3);
        load_edge(r3, y, lane, d0, d1, d2, d3);
        compute_edge(r0, a0, a1, a2, a3, bias, acc);
        compute_edge(r1, b0, b1, b2, b3, bias, acc);
        compute_edge(r2, c0, c1, c2, c3, bias, acc);
        compute_edge(r3, d0, d1, d2, d3, bias, acc);
    }
    if (i + 2 <= s1) {
        uint4 r0 = ldnt4(&rec[i + 0]);
        uint4 r1 = ldnt4(&rec[i + 1]);
        uint2 a0, a1, a2, a3, b0, b1, b2, b3;
        load_edge(r0, y, lane, a0, a1, a2, a3);
        load_edge(r1, y, lane, b0, b1, b2, b3);
        compute_edge(r0, a0, a1, a2, a3, bias, acc);
        compute_edge(r1, b0, b1, b2, b3, bias, acc);
        i += 2;
    }
    if (i < s1) {
        uint4 r0 = ldnt4(&rec[i]);
        uint2 a0, a1, a2, a3;
        load_edge(r0, y, lane, a0, a1, a2, a3);
        compute_edge(r0, a0, a1, a2, a3, bias, acc);
    }

    float inv = 1.0f / (float)(deg > 1 ? deg : 1);
    float4 r;
    r.x = fmaxf(acc.x * inv, 0.f);
    r.y = fmaxf(acc.y * inv, 0.f);
    r.z = fmaxf(acc.z * inv, 0.f);
    r.w = fmaxf(acc.w * inv, 0.f);
    return r;
}

// ---- layer-0 aggregate (degree-balanced via perm) ----
__global__ __launch_bounds__(256) void agg_k(const uint4* __restrict__ rec,
                                             const int* __restrict__ start,
                                             const int* __restrict__ cnt,
                                             const int* __restrict__ perm,
                                             const unsigned* __restrict__ y,
                                             const float* __restrict__ b,
                                             float* __restrict__ hout) {
    int t = blockIdx.x * 256 + threadIdx.x;
    int gid = t >> 4;
    int lane = t & 15;
    int g = perm[gid];
    float4 r = agg_core(rec, start, cnt, y, b, g, lane);
    ((float4*)hout)[(size_t)g * 16 + lane] = r;
}

// ---- layer-1 aggregate fused with final fc (block = 16 nodes, degree-balanced) ----
__global__ __launch_bounds__(256) void agg_fc_k(const uint4* __restrict__ rec,
                                                const int* __restrict__ start,
                                                const int* __restrict__ cnt,
                                                const int* __restrict__ perm,
                                                const unsigned* __restrict__ y,
                                                const float* __restrict__ b,
                                                const float* __restrict__ Wfc,
                                                const float* __restrict__ bfc,
                                                float* __restrict__ out) {
    __shared__ float sh_h[16 * 65];
    __shared__ float sWfcT[NCLS * 65];   // transposed, padded: [c*65 + j]
    __shared__ float sbfc[NCLS];
    __shared__ int sgid[16];
    int t = threadIdx.x;

    for (int i = t; i < 64 * NCLS; i += 256) {
        int j = i / NCLS;
        int c = i - j * NCLS;
        sWfcT[c * 65 + j] = Wfc[i];
    }
    if (t < NCLS) sbfc[t] = bfc[t];

    int nl = t >> 4;
    int lane = t & 15;
    int g = perm[blockIdx.x * 16 + nl];   // grid exact: 3125*16 = 50000
    if (lane == 0) sgid[nl] = g;

    float4 r = agg_core(rec, start, cnt, y, b, g, lane);
    sh_h[nl * 65 + lane * 4 + 0] = r.x;
    sh_h[nl * 65 + lane * 4 + 1] = r.y;
    sh_h[nl * 65 + lane * 4 + 2] = r.z;
    sh_h[nl * 65 + lane * 4 + 3] = r.w;
    __syncthreads();

    for (int item = t; item < 16 * NCLS; item += 256) {
        int rn = item / NCLS;
        int c = item - rn * NCLS;
        float acc = sbfc[c];
        const float* hr = &sh_h[rn * 65];
        const float* wc = &sWfcT[c * 65];
#pragma unroll
        for (int j = 0; j < 64; ++j) acc = fmaf(hr[j], wc[j], acc);
        out[(size_t)sgid[rn] * NCLS + c] = acc;
    }
}

extern "C" void kernel_launch(void* const* d_in, const int* in_sizes, int n_in,
                              void* d_out, int out_size, void* d_ws, size_t ws_size,
                              hipStream_t stream) {
    const float* nf  = (const float*)d_in[0];
    const float* ef  = (const float*)d_in[1];
    const int*   src = (const int*)d_in[2];
    const int*   dst = (const int*)d_in[3];
    const float* W0  = (const float*)d_in[4];
    const float* b0  = (const float*)d_in[5];
    const float* W1  = (const float*)d_in[6];
    const float* b1  = (const float*)d_in[7];
    const float* Wfc = (const float*)d_in[8];
    const float* bfc = (const float*)d_in[9];
    float* out = (float*)d_out;

    char* ws = (char*)d_ws;
    size_t off = 0;
    auto alloc = [&](size_t bytes) -> void* {
        void* p = ws + off;
        off = (off + bytes + 255) & ~(size_t)255;
        return p;
    };
    // zeroed region: cnt | bflag | bval | dbin
    int*      zbuf   = (int*)     alloc((size_t)(50176 + 512 + 256) * 4);
    int*      cnt    = zbuf;
    int*      bflag  = zbuf + 50176;
    int*      bval   = zbuf + 50176 + 256;
    int*      dbin   = zbuf + 50176 + 512;
    int*      start  = (int*)     alloc((size_t)(N_NODES + 1) * 4);
    int*      cursor = (int*)     alloc((size_t)N_NODES * 4);
    int*      dcur   = (int*)     alloc((size_t)256 * 4);
    int*      perm   = (int*)     alloc((size_t)N_NODES * 4);
    uint4*    recA   = (uint4*)   alloc((size_t)N_EDGES * 16);
    uint4*    recB   = (uint4*)   alloc((size_t)N_EDGES * 16);
    unsigned* y      = (unsigned*)alloc((size_t)N_NODES * 256 * 2);
    float*    hbuf   = (float*)   alloc((size_t)N_NODES * 64 * 4);

    hipMemsetAsync(zbuf, 0, (size_t)(50176 + 512 + 256) * 4, stream);

    hist_k<<<EBLK, 256, 0, stream>>>(dst, cnt);
    scan_k<<<NBLK, 256, 0, stream>>>(cnt, start, cursor, bflag, bval);
    dhist_k<<<NBLK, 256, 0, stream>>>(cnt, dbin);
    dscan_k<<<1, 256, 0, stream>>>(dbin, dcur);
    dscatter_k<<<NBLK, 256, 0, stream>>>(cnt, dcur, perm);
    scatter_k<<<EBLK, 256, 0, stream>>>(src, dst, ef, cursor, recA);
    repack_k<<<EBLK, 256, 0, stream>>>(recA, ef + (size_t)N_EDGES * 4, recB);

    dim3 tgrid((N_NODES + 63) / 64, 2);   // 782 x 2 (split-k)
    int agrid = N_NODES / 16;             // 3125, exact

    // layer 0
    transform_k<<<tgrid, 256, 0, stream>>>(nf, W0, y);
    agg_k<<<agrid, 256, 0, stream>>>(recA, start, cnt, perm, y, b0, hbuf);

    // layer 1 + fused classifier
    transform_k<<<tgrid, 256, 0, stream>>>(hbuf, W1, y);
    agg_fc_k<<<agrid, 256, 0, stream>>>(recB, start, cnt, perm, y, b1, Wfc, bfc, out);
}

// Round 7
// 321.813 us; speedup vs baseline: 1.9933x; 1.9933x over previous
//
#include <hip/hip_runtime.h>
#include <hip/hip_fp16.h>

#define N_NODES 50000
#define N_EDGES 500000
#define DIM 64
#define KDIM 4
#define HID 64
#define NCLS 40
#define NBLK ((N_NODES + 255) / 256)   // 196
#define EBLK ((N_EDGES + 255) / 256)   // 1954

typedef unsigned uv4 __attribute__((ext_vector_type(4)));

__device__ inline unsigned pack2(float a, float b) {
    __half2 h = __floats2half2_rn(a, b);
    return *(unsigned*)&h;
}
__device__ inline float2 unpack2(unsigned u) {
    __half2 h = *(__half2*)&u;
    return __half22float2(h);
}
__device__ inline uint4 ldnt4(const uint4* p) {
    uv4 v = __builtin_nontemporal_load((const uv4*)p);
    return make_uint4(v.x, v.y, v.z, v.w);
}
__device__ inline void stnt4(uint4* p, uint4 v) {
    uv4 w = {v.x, v.y, v.z, v.w};
    __builtin_nontemporal_store(w, (uv4*)p);
}

// ---- histogram of dst (in-degree) ----
__global__ void hist_k(const int* __restrict__ dst, int* __restrict__ cnt) {
    int e = blockIdx.x * 256 + threadIdx.x;
    if (e < N_EDGES) atomicAdd(&cnt[dst[e]], 1);
}

// ---- single-kernel scan: per-block scan + publish + parallel lookback ----
__global__ __launch_bounds__(256) void scan_k(const int* __restrict__ cnt,
                                              int* __restrict__ start,
                                              int* __restrict__ cursor,
                                              volatile int* __restrict__ bflag,
                                              volatile int* __restrict__ bval) {
    __shared__ int ls[256];
    __shared__ int sbase;
    __shared__ int ok_all;
    int b = blockIdx.x, t = threadIdx.x;
    int n = b * 256 + t;
    int v = (n < N_NODES) ? cnt[n] : 0;
    ls[t] = v;
    __syncthreads();
#pragma unroll
    for (int off = 1; off < 256; off <<= 1) {
        int u = (t >= off) ? ls[t - off] : 0;
        __syncthreads();
        ls[t] += u;
        __syncthreads();
    }
    int incl = ls[t];
    int total = ls[255];
    __syncthreads();

    if (t == 0) {
        bval[b] = total;
        __threadfence();
        bflag[b] = 1;
    }

    if (b > 0) {
        for (;;) {
            int f = (t < b) ? bflag[t] : 1;
            if (t == 0) ok_all = 1;
            __syncthreads();
            if (!f) ok_all = 0;
            __syncthreads();
            if (ok_all) break;
        }
        __threadfence();
        int pv = (t < b) ? bval[t] : 0;
        ls[t] = pv;
        __syncthreads();
#pragma unroll
        for (int off = 128; off > 0; off >>= 1) {
            if (t < off) ls[t] += ls[t + off];
            __syncthreads();
        }
        if (t == 0) sbase = ls[0];
        __syncthreads();
    } else {
        if (t == 0) sbase = 0;
        __syncthreads();
    }

    int excl = sbase + incl - v;
    if (n < N_NODES) { start[n] = excl; cursor[n] = excl; }
    if (n == 0) start[N_NODES] = N_EDGES;
}

// ---- degree-sort, contention-free: LDS histogram + block reservation ----
// key = 255 - clamped degree (LPT / descending degree order)
__global__ __launch_bounds__(256) void dhist_k(const int* __restrict__ cnt,
                                               int* __restrict__ dbin) {
    __shared__ int lb[256];
    int t = threadIdx.x;
    lb[t] = 0;
    __syncthreads();
    int n = blockIdx.x * 256 + t;
    if (n < N_NODES) {
        int d = cnt[n]; if (d > 255) d = 255;
        atomicAdd(&lb[255 - d], 1);
    }
    __syncthreads();
    if (lb[t]) atomicAdd(&dbin[t], lb[t]);
}

// single block exclusive scan of 256 bins -> dcursor
__global__ __launch_bounds__(256) void dscan_k(const int* __restrict__ dbin,
                                               int* __restrict__ dcursor) {
    __shared__ int ls[256];
    int t = threadIdx.x;
    int v = dbin[t];
    ls[t] = v;
    __syncthreads();
#pragma unroll
    for (int off = 1; off < 256; off <<= 1) {
        int u = (t >= off) ? ls[t - off] : 0;
        __syncthreads();
        ls[t] += u;
        __syncthreads();
    }
    dcursor[t] = ls[t] - v;   // exclusive
}

// per-block: LDS rank within bin + one global reservation per non-empty bin
__global__ __launch_bounds__(256) void dscatter_k(const int* __restrict__ cnt,
                                                  int* __restrict__ dcursor,
                                                  int* __restrict__ perm) {
    __shared__ int lb[256];
    __shared__ int gbase[256];
    int t = threadIdx.x;
    lb[t] = 0;
    __syncthreads();
    int n = blockIdx.x * 256 + t;
    int b = 0, r = 0;
    if (n < N_NODES) {
        int d = cnt[n]; if (d > 255) d = 255;
        b = 255 - d;
        r = atomicAdd(&lb[b], 1);
    }
    __syncthreads();
    if (lb[t]) gbase[t] = atomicAdd(&dcursor[t], lb[t]);
    __syncthreads();
    if (n < N_NODES) perm[gbase[b] + r] = n;
}

// ---- counting-sort scatter: write ONLY recA (16B random store/edge),
//      keep edge index in .w so recB can be built by a streaming repack ----
__global__ void scatter_k(const int* __restrict__ src, const int* __restrict__ dst,
                          const float* __restrict__ ef, int* __restrict__ cursor,
                          uint4* __restrict__ recA) {
    int e = blockIdx.x * 256 + threadIdx.x;
    if (e < N_EDGES) {
        int d = dst[e];
        int pos = atomicAdd(&cursor[d], 1);
        int sn = src[e];
        float4 f0 = ((const float4*)ef)[e];
        stnt4(&recA[pos], make_uint4((unsigned)sn, pack2(f0.x, f0.y), pack2(f0.z, f0.w), (unsigned)e));
    }
}

// ---- streaming repack: build layer-1 records from recA order ----
__global__ void repack_k(const uint4* __restrict__ recA, const float* __restrict__ ef1,
                         uint4* __restrict__ recB) {
    int i = blockIdx.x * 256 + threadIdx.x;
    if (i < N_EDGES) {
        uint4 r = ldnt4(&recA[i]);
        int e = (int)r.w;
        float4 f1 = ((const float4*)ef1)[e];
        stnt4(&recB[i], make_uint4(r.x, pack2(f1.x, f1.y), pack2(f1.z, f1.w), 0u));
    }
}

// ---- node transform, split-k: blockIdx.y = kpair (k in {2*kpair, 2*kpair+1}) ----
__global__ __launch_bounds__(256) void transform_k(const float* __restrict__ hin,
                                                   const float* __restrict__ W,
                                                   unsigned* __restrict__ y) {
    __shared__ float sW[2 * 64 * 64];      // 32 KB: two k-slices
    __shared__ float sh[64 * 65];          // 16.6 KB
    int t = threadIdx.x;
    int kpair = blockIdx.y;

    const float4* W4 = (const float4*)(W + (size_t)kpair * 2 * 4096);
    float4* sW4 = (float4*)sW;
#pragma unroll
    for (int i = 0; i < 8; ++i) sW4[t + 256 * i] = W4[t + 256 * i];

    int n0 = blockIdx.x * 64;
#pragma unroll
    for (int i = 0; i < 4; ++i) {
        int idx = t + 256 * i;        // 0..1023
        int nl = idx >> 4;            // 0..63
        int dg = idx & 15;
        int n = n0 + nl;
        float4 v = make_float4(0.f, 0.f, 0.f, 0.f);
        if (n < N_NODES) v = ((const float4*)hin)[(size_t)n * 16 + dg];
        sh[nl * 65 + dg * 4 + 0] = v.x;
        sh[nl * 65 + dg * 4 + 1] = v.y;
        sh[nl * 65 + dg * 4 + 2] = v.z;
        sh[nl * 65 + dg * 4 + 3] = v.w;
    }
    __syncthreads();

    int nl = t & 31;
    int cg = t >> 5;                  // 0..7
    int k_local = cg >> 2;            // 0..1
    int hc0 = (cg & 3) * 16;

    float acc0[16], acc1[16];
#pragma unroll
    for (int j = 0; j < 16; ++j) { acc0[j] = 0.f; acc1[j] = 0.f; }

    for (int d = 0; d < 64; ++d) {
        float a0 = sh[nl * 65 + d];
        float a1 = sh[(nl + 32) * 65 + d];
        const float* wr = &sW[k_local * 4096 + d * 64 + hc0];
#pragma unroll
        for (int j = 0; j < 16; ++j) {
            float w = wr[j];
            acc0[j] = fmaf(a0, w, acc0[j]);
            acc1[j] = fmaf(a1, w, acc1[j]);
        }
    }

    int n_a = n0 + nl, n_b = n0 + nl + 32;
    int cbase = (kpair * 2 + k_local) * 64 + hc0;
    if (n_a < N_NODES) {
        uint4* o = (uint4*)(y + ((size_t)n_a * 256 + cbase) / 2);
        o[0] = make_uint4(pack2(acc0[0], acc0[1]), pack2(acc0[2], acc0[3]),
                          pack2(acc0[4], acc0[5]), pack2(acc0[6], acc0[7]));
        o[1] = make_uint4(pack2(acc0[8], acc0[9]), pack2(acc0[10], acc0[11]),
                          pack2(acc0[12], acc0[13]), pack2(acc0[14], acc0[15]));
    }
    if (n_b < N_NODES) {
        uint4* o = (uint4*)(y + ((size_t)n_b * 256 + cbase) / 2);
        o[0] = make_uint4(pack2(acc1[0], acc1[1]), pack2(acc1[2], acc1[3]),
                          pack2(acc1[4], acc1[5]), pack2(acc1[6], acc1[7]));
        o[1] = make_uint4(pack2(acc1[8], acc1[9]), pack2(acc1[10], acc1[11]),
                          pack2(acc1[12], acc1[13]), pack2(acc1[14], acc1[15]));
    }
}

// ---- edge load/compute split for MLP ----
__device__ inline void load_edge(const uint4 r, const unsigned* __restrict__ y,
                                 int lane, uint2& q0, uint2& q1, uint2& q2, uint2& q3) {
    int sn = (int)r.x;
    const uint2* yb = (const uint2*)(y + (size_t)sn * 128);
    q0 = yb[lane];
    q1 = yb[16 + lane];
    q2 = yb[32 + lane];
    q3 = yb[48 + lane];
}

__device__ inline void compute_edge(const uint4 r, uint2 q0, uint2 q1, uint2 q2, uint2 q3,
                                    const float4 bias, float4& acc) {
    float2 e01 = unpack2(r.y);
    float2 e23 = unpack2(r.z);
    float2 a0 = unpack2(q0.x), a1 = unpack2(q0.y);
    float2 b0 = unpack2(q1.x), b1 = unpack2(q1.y);
    float2 c0 = unpack2(q2.x), c1 = unpack2(q2.y);
    float2 d0 = unpack2(q3.x), d1 = unpack2(q3.y);

    float4 z = bias;
    z.x = fmaf(e01.x, a0.x, z.x); z.y = fmaf(e01.x, a0.y, z.y);
    z.z = fmaf(e01.x, a1.x, z.z); z.w = fmaf(e01.x, a1.y, z.w);
    z.x = fmaf(e01.y, b0.x, z.x); z.y = fmaf(e01.y, b0.y, z.y);
    z.z = fmaf(e01.y, b1.x, z.z); z.w = fmaf(e01.y, b1.y, z.w);
    z.x = fmaf(e23.x, c0.x, z.x); z.y = fmaf(e23.x, c0.y, z.y);
    z.z = fmaf(e23.x, c1.x, z.z); z.w = fmaf(e23.x, c1.y, z.w);
    z.x = fmaf(e23.y, d0.x, z.x); z.y = fmaf(e23.y, d0.y, z.y);
    z.z = fmaf(e23.y, d1.x, z.z); z.w = fmaf(e23.y, d1.y, z.w);

    acc.x += fmaxf(z.x, 0.f);
    acc.y += fmaxf(z.y, 0.f);
    acc.z += fmaxf(z.z, 0.f);
    acc.w += fmaxf(z.w, 0.f);
}

// ---- aggregate core: unroll-4, batched loads; rec loads nontemporal ----
__device__ inline float4 agg_core(const uint4* __restrict__ rec,
                                  const int* __restrict__ start,
                                  const int* __restrict__ cnt,
                                  const unsigned* __restrict__ y,
                                  const float* __restrict__ b,
                                  int g, int lane) {
    int s0 = start[g];
    int deg = cnt[g];
    int s1 = s0 + deg;

    float4 bias = ((const float4*)b)[lane];
    float4 acc = make_float4(0.f, 0.f, 0.f, 0.f);

    int i = s0;
    for (; i + 4 <= s1; i += 4) {
        uint4 r0 = ldnt4(&rec[i + 0]);
        uint4 r1 = ldnt4(&rec[i + 1]);
        uint4 r2 = ldnt4(&rec[i + 2]);
        uint4 r3 = ldnt4(&rec[i + 3]);
        uint2 a0, a1, a2, a3, b0, b1, b2, b3, c0, c1, c2, c3, d0, d1, d2, d3;
        load_edge(r0, y, lane, a0, a1, a2, a3);
        load_edge(r1, y, lane, b0, b1, b2, b3);
        load_edge(r2, y, lane, c0, c1, c2, c3);
        load_edge(r3, y, lane, d0, d1, d2, d3);
        compute_edge(r0, a0, a1, a2, a3, bias, acc);
        compute_edge(r1, b0, b1, b2, b3, bias, acc);
        compute_edge(r2, c0, c1, c2, c3, bias, acc);
        compute_edge(r3, d0, d1, d2, d3, bias, acc);
    }
    if (i + 2 <= s1) {
        uint4 r0 = ldnt4(&rec[i + 0]);
        uint4 r1 = ldnt4(&rec[i + 1]);
        uint2 a0, a1, a2, a3, b0, b1, b2, b3;
        load_edge(r0, y, lane, a0, a1, a2, a3);
        load_edge(r1, y, lane, b0, b1, b2, b3);
        compute_edge(r0, a0, a1, a2, a3, bias, acc);
        compute_edge(r1, b0, b1, b2, b3, bias, acc);
        i += 2;
    }
    if (i < s1) {
        uint4 r0 = ldnt4(&rec[i]);
        uint2 a0, a1, a2, a3;
        load_edge(r0, y, lane, a0, a1, a2, a3);
        compute_edge(r0, a0, a1, a2, a3, bias, acc);
    }

    float inv = 1.0f / (float)(deg > 1 ? deg : 1);
    float4 r;
    r.x = fmaxf(acc.x * inv, 0.f);
    r.y = fmaxf(acc.y * inv, 0.f);
    r.z = fmaxf(acc.z * inv, 0.f);
    r.w = fmaxf(acc.w * inv, 0.f);
    return r;
}

// ---- layer-0 aggregate (degree-balanced via perm) ----
__global__ __launch_bounds__(256) void agg_k(const uint4* __restrict__ rec,
                                             const int* __restrict__ start,
                                             const int* __restrict__ cnt,
                                             const int* __restrict__ perm,
                                             const unsigned* __restrict__ y,
                                             const float* __restrict__ b,
                                             float* __restrict__ hout) {
    int t = blockIdx.x * 256 + threadIdx.x;
    int gid = t >> 4;
    int lane = t & 15;
    int g = perm[gid];
    float4 r = agg_core(rec, start, cnt, y, b, g, lane);
    ((float4*)hout)[(size_t)g * 16 + lane] = r;
}

// ---- layer-1 aggregate fused with final fc (block = 16 nodes, degree-balanced) ----
__global__ __launch_bounds__(256) void agg_fc_k(const uint4* __restrict__ rec,
                                                const int* __restrict__ start,
                                                const int* __restrict__ cnt,
                                                const int* __restrict__ perm,
                                                const unsigned* __restrict__ y,
                                                const float* __restrict__ b,
                                                const float* __restrict__ Wfc,
                                                const float* __restrict__ bfc,
                                                float* __restrict__ out) {
    __shared__ float sh_h[16 * 65];
    __shared__ float sWfcT[NCLS * 65];   // transposed, padded: [c*65 + j]
    __shared__ float sbfc[NCLS];
    __shared__ int sgid[16];
    int t = threadIdx.x;

    for (int i = t; i < 64 * NCLS; i += 256) {
        int j = i / NCLS;
        int c = i - j * NCLS;
        sWfcT[c * 65 + j] = Wfc[i];
    }
    if (t < NCLS) sbfc[t] = bfc[t];

    int nl = t >> 4;
    int lane = t & 15;
    int g = perm[blockIdx.x * 16 + nl];   // grid exact: 3125*16 = 50000
    if (lane == 0) sgid[nl] = g;

    float4 r = agg_core(rec, start, cnt, y, b, g, lane);
    sh_h[nl * 65 + lane * 4 + 0] = r.x;
    sh_h[nl * 65 + lane * 4 + 1] = r.y;
    sh_h[nl * 65 + lane * 4 + 2] = r.z;
    sh_h[nl * 65 + lane * 4 + 3] = r.w;
    __syncthreads();

    for (int item = t; item < 16 * NCLS; item += 256) {
        int rn = item / NCLS;
        int c = item - rn * NCLS;
        float acc = sbfc[c];
        const float* hr = &sh_h[rn * 65];
        const float* wc = &sWfcT[c * 65];
#pragma unroll
        for (int j = 0; j < 64; ++j) acc = fmaf(hr[j], wc[j], acc);
        out[(size_t)sgid[rn] * NCLS + c] = acc;
    }
}

extern "C" void kernel_launch(void* const* d_in, const int* in_sizes, int n_in,
                              void* d_out, int out_size, void* d_ws, size_t ws_size,
                              hipStream_t stream) {
    const float* nf  = (const float*)d_in[0];
    const float* ef  = (const float*)d_in[1];
    const int*   src = (const int*)d_in[2];
    const int*   dst = (const int*)d_in[3];
    const float* W0  = (const float*)d_in[4];
    const float* b0  = (const float*)d_in[5];
    const float* W1  = (const float*)d_in[6];
    const float* b1  = (const float*)d_in[7];
    const float* Wfc = (const float*)d_in[8];
    const float* bfc = (const float*)d_in[9];
    float* out = (float*)d_out;

    char* ws = (char*)d_ws;
    size_t off = 0;
    auto alloc = [&](size_t bytes) -> void* {
        void* p = ws + off;
        off = (off + bytes + 255) & ~(size_t)255;
        return p;
    };
    // zeroed region: cnt | bflag | bval | dbin
    int*      zbuf   = (int*)     alloc((size_t)(50176 + 512 + 256) * 4);
    int*      cnt    = zbuf;
    int*      bflag  = zbuf + 50176;
    int*      bval   = zbuf + 50176 + 256;
    int*      dbin   = zbuf + 50176 + 512;
    int*      start  = (int*)     alloc((size_t)(N_NODES + 1) * 4);
    int*      cursor = (int*)     alloc((size_t)N_NODES * 4);
    int*      dcur   = (int*)     alloc((size_t)256 * 4);
    int*      perm   = (int*)     alloc((size_t)N_NODES * 4);
    uint4*    recA   = (uint4*)   alloc((size_t)N_EDGES * 16);
    uint4*    recB   = (uint4*)   alloc((size_t)N_EDGES * 16);
    unsigned* y      = (unsigned*)alloc((size_t)N_NODES * 256 * 2);
    float*    hbuf   = (float*)   alloc((size_t)N_NODES * 64 * 4);

    hipMemsetAsync(zbuf, 0, (size_t)(50176 + 512 + 256) * 4, stream);

    hist_k<<<EBLK, 256, 0, stream>>>(dst, cnt);
    scan_k<<<NBLK, 256, 0, stream>>>(cnt, start, cursor, bflag, bval);
    dhist_k<<<NBLK, 256, 0, stream>>>(cnt, dbin);
    dscan_k<<<1, 256, 0, stream>>>(dbin, dcur);
    dscatter_k<<<NBLK, 256, 0, stream>>>(cnt, dcur, perm);
    scatter_k<<<EBLK, 256, 0, stream>>>(src, dst, ef, cursor, recA);
    repack_k<<<EBLK, 256, 0, stream>>>(recA, ef + (size_t)N_EDGES * 4, recB);

    dim3 tgrid((N_NODES + 63) / 64, 2);   // 782 x 2 (split-k)
    int agrid = N_NODES / 16;             // 3125, exact

    // layer 0
    transform_k<<<tgrid, 256, 0, stream>>>(nf, W0, y);
    agg_k<<<agrid, 256, 0, stream>>>(recA, start, cnt, perm, y, b0, hbuf);

    // layer 1 + fused classifier
    transform_k<<<tgrid, 256, 0, stream>>>(hbuf, W1, y);
    agg_fc_k<<<agrid, 256, 0, stream>>>(recB, start, cnt, perm, y, b1, Wfc, bfc, out);
}